// Round 10
// baseline (227.856 us; speedup 1.0000x reference)
//
#include <hip/hip_runtime.h>
#include <hip/hip_bf16.h>

// Problem constants (fixed by the reference)
#define BATCH 8
#define NPTS  4096      // N
#define CCH   128       // C
#define KNN_K 16        // K

typedef __attribute__((ext_vector_type(8))) short  bf16x8;  // 8 bf16 = 4 VGPRs
typedef __attribute__((ext_vector_type(4))) float  f32x4;   // MFMA acc

// ---------------------------------------------------------------------------
// ws layout (bytes):
//   [0)        Wb    : C*C  bf16            =    32,768
//   [32768)    scale : C fp32               =       512
//   [33280)    bias  : C fp32               =       512
//   [33792)    pts   : B*N float4(x,y,z,s)  =   524,288
//   [558080)   knn   : B*N*K u16            = 1,048,576
//   [1606656)  Zb    : B*N*C bf16           = 8,388,608   (Z = W@x, [B,N,C])
// total ~9.99 MB  (xTb eliminated: transpose folded into the fused GEMM)
// ---------------------------------------------------------------------------

static __device__ __forceinline__ short f2bf(float v) {
    __hip_bfloat16 h = __float2bfloat16(v);   // RNE
    return __builtin_bit_cast(short, h);
}

// Prep: W -> bf16; fold BN affine; xyz -> SoA float4 with |p|^2
__global__ __launch_bounds__(256) void small_prep_kernel(
    const float* __restrict__ xyz, const float* __restrict__ W,
    const float* __restrict__ gamma, const float* __restrict__ beta,
    const float* __restrict__ rmean, const float* __restrict__ rvar,
    short* __restrict__ Wb, float* __restrict__ scale, float* __restrict__ bias,
    float4* __restrict__ pts)
{
    const int t = blockIdx.x * 256 + threadIdx.x;   // grid covers B*N = 32768
    if (t < CCH * CCH) Wb[t] = f2bf(W[t]);
    if (t < CCH) {
        const float s = gamma[t] / sqrtf(rvar[t] + 1e-5f);
        scale[t] = s;
        bias[t]  = beta[t] - rmean[t] * s;
    }
    {
        #pragma clang fp contract(off)
        const float px = xyz[3 * t + 0];
        const float py = xyz[3 * t + 1];
        const float pz = xyz[3 * t + 2];
        const float s  = px * px + py * py + pz * pz;   // matches ref s = sum(xyz*xyz)
        pts[t] = make_float4(px, py, pz, s);
    }
}

// FUSED dispatch: blocks [0,512) = dense GEMM with inline transpose;
// blocks [512,2560) = KNN. GEMM is MFMA/memory-pipe work, KNN is
// VALU/LDS-pipe work -- on the same CU they co-schedule (time ~ max, not
// sum; m114), so the GEMM hides under the KNN's 120 us.
__global__ __launch_bounds__(256) void fused_kernel(
    const float* __restrict__ x, const float4* __restrict__ pts,
    const short* __restrict__ Wb,
    unsigned short* __restrict__ knn, short* __restrict__ Zb)
{
    // LDS: 128(k) x 64(n) bf16 x-tile, pitch 66 (conflict-free both phases)
    __shared__ short tile[CCH * 66];

    if (blockIdx.x < 512) {
        // ---- GEMM path: Z[n,c] = sum_k x[k,n] * W[c,k], 64 rows per block ----
        const int tid = threadIdx.x;
        const int R   = blockIdx.x * 64;        // flat row base (B*N)
        const int b   = R >> 12;
        const int n0  = R & 4095;

        // Stage x tile: coalesced fp32 float4 reads along n; packed b32 LDS
        // writes (2-way bank alias max). tile[k][nn] = bf16(x[b,k,n0+nn]).
        #pragma unroll
        for (int it = 0; it < 8; ++it) {
            const int idx = it * 256 + tid;     // 2048 float4s
            const int cc  = idx >> 4;           // k / channel 0..127
            const int nf  = (idx & 15) << 2;    // n offset 0..60
            const float4 v = *(const float4*)(x + (size_t)(b * CCH + cc) * NPTS + n0 + nf);
            const unsigned lo = (unsigned)(unsigned short)f2bf(v.x)
                              | ((unsigned)(unsigned short)f2bf(v.y) << 16);
            const unsigned hi = (unsigned)(unsigned short)f2bf(v.z)
                              | ((unsigned)(unsigned short)f2bf(v.w) << 16);
            *(unsigned*)(tile + cc * 66 + nf)     = lo;
            *(unsigned*)(tile + cc * 66 + nf + 2) = hi;
        }
        __syncthreads();

        const int lane = tid & 63;
        const int wid  = tid >> 6;
        const int kl   = lane & 15;
        const int q8   = (lane >> 4) * 8;
        const int nn   = wid * 16 + kl;         // this lane's A-row (point)

        const f32x4 zero = {0.f, 0.f, 0.f, 0.f};
        f32x4 acc[8];
        #pragma unroll
        for (int t = 0; t < 8; ++t) acc[t] = zero;

        #pragma unroll
        for (int kk = 0; kk < 4; ++kk) {
            bf16x8 a;
            #pragma unroll
            for (int j = 0; j < 8; ++j)         // 8 u16 LDS reads, conflict-free
                a[j] = tile[(kk * 32 + q8 + j) * 66 + nn];
            #pragma unroll
            for (int t = 0; t < 8; ++t) {
                const bf16x8 bf = *(const bf16x8*)(Wb + (t * 16 + kl) * CCH + kk * 32 + q8);
                acc[t] = __builtin_amdgcn_mfma_f32_16x16x32_bf16(a, bf, acc[t], 0, 0, 0);
            }
        }

        const int rb = R + wid * 16 + (lane >> 4) * 4;  // C/D row = quad*4+reg
        #pragma unroll
        for (int t = 0; t < 8; ++t)
            #pragma unroll
            for (int r = 0; r < 4; ++r)
                Zb[(size_t)(rb + r) * CCH + t * 16 + kl] = f2bf(acc[t][r]);
        return;
    }

    // ---- KNN path (identical to round 9): 4 queries/wave, cross-lane list ----
    const int lane = threadIdx.x & 63;
    const int wid  = threadIdx.x >> 6;
    const int g    = lane >> 4;                 // group (query) 0..3
    const int s    = lane & 15;                 // slot within group
    const int kb   = blockIdx.x - 512;
    const int wq   = kb * 16 + wid * 4;         // first query of this wave
    const int b    = wq >> 12;                  // 4 queries never cross a batch
    const int i    = (wq & 4095) + g;           // this lane's query
    const float4* pb = pts + (b << 12);

    const float4 q = pb[i];                     // group-uniform

    float bd = 3.4e38f;                         // slot s: s-th smallest
    int   bj = 0;
    float tau = 3.4e38f;                        // group-uniform (lane copy)
    const bool sgt0 = (s > 0);

    float4 p = pb[s];                           // chunk 0 candidates
    for (int ch = 0; ch < 256; ++ch) {
        const int nxt = (ch + 1 < 256) ? ((ch + 1) << 4) + s : s;
        const float4 pn = pb[nxt];              // prefetch next chunk
        float d2;
        {
            #pragma clang fp contract(off)
            const float cs  = p.w;
            const float dot = q.x * p.x + q.y * p.y + q.z * p.z;
            d2 = (q.w + cs) - 2.0f * dot;       // s_i + s_j - 2*dot, as ref
        }
        const unsigned long long mask = __ballot(d2 < tau);
        unsigned sub = (unsigned)((mask >> (g << 4)) & 0xFFFFull);
        while (__any(sub != 0)) {
            const bool has = (sub != 0);
            const int  l   = has ? (__ffs(sub) - 1) : 0;
            const float dv_raw = __shfl(d2, l, 16);      // group-local fetch
            const float dv = has ? dv_raw : 3.4e38f;
            const int   jv = (ch << 4) + l;
            sub = has ? (sub & (sub - 1)) : 0u;
            // sorted insert across the group's 16 lanes (ascending)
            const float pd = __shfl_up(bd, 1, 16);
            const int   pj = __shfl_up(bj, 1, 16);
            const bool lt  = dv < bd;
            const bool ltp = sgt0 && (dv < pd);
            bd = lt ? (ltp ? pd : dv) : bd;
            bj = lt ? (ltp ? pj : jv) : bj;
        }
        tau = __shfl(bd, 15, 16);               // once per chunk; stale
        p = pn;                                 // survivors self-reject
    }

    unsigned short* o = knn + ((((size_t)b << 12) + i) << 4);
    o[s] = (unsigned short)bj;                  // 4 queries x 16 slots
}

// Gather + BN + ReLU + max-over-16, then coalesced store via LDS transpose.
__global__ __launch_bounds__(256) void gmax_kernel(
    const short* __restrict__ Zb, const unsigned short* __restrict__ knn,
    const float* __restrict__ scale, const float* __restrict__ bias,
    float* __restrict__ out)
{
    __shared__ float sm[16][132];
    const int lane = threadIdx.x & 63;
    const int wid  = threadIdx.x >> 6;
    const int n0   = blockIdx.x * 16;           // flat point base (B*N)
    const int b    = blockIdx.x >> 8;           // 256 blocks per batch
    const float s0 = scale[2 * lane],   s1 = scale[2 * lane + 1];
    const float t0 = bias[2 * lane],    t1 = bias[2 * lane + 1];

    for (int p = 0; p < 4; ++p) {
        const int n = n0 + wid * 4 + p;         // flat
        const unsigned short* kr = knn + (size_t)n * 16;
        float m0 = 0.f, m1 = 0.f;               // relu floor
        #pragma unroll
        for (int k = 0; k < 16; ++k) {
            const int r = (int)kr[k];           // within-batch row
            const unsigned v = *(const unsigned*)(Zb + ((size_t)(b * NPTS + r)) * CCH + 2 * lane);
            const float z0 = __uint_as_float(v << 16);
            const float z1 = __uint_as_float(v & 0xFFFF0000u);
            m0 = fmaxf(m0, s0 * z0 + t0);
            m1 = fmaxf(m1, s1 * z1 + t1);
        }
        sm[wid * 4 + p][2 * lane]     = m0;
        sm[wid * 4 + p][2 * lane + 1] = m1;
    }
    __syncthreads();

    const int c    = threadIdx.x & 127;
    const int half = threadIdx.x >> 7;
    float v[8];
    #pragma unroll
    for (int i = 0; i < 8; ++i) v[i] = sm[half * 8 + i][c];
    float4 f0 = {v[0], v[1], v[2], v[3]};
    float4 f1 = {v[4], v[5], v[6], v[7]};
    float* op = out + ((size_t)(b * CCH + c)) * NPTS + (n0 & 4095) + half * 8;
    *(float4*)op       = f0;
    *(float4*)(op + 4) = f1;
}

extern "C" void kernel_launch(void* const* d_in, const int* in_sizes, int n_in,
                              void* d_out, int out_size, void* d_ws, size_t ws_size,
                              hipStream_t stream)
{
    const float* xyz   = (const float*)d_in[0];
    const float* x     = (const float*)d_in[1];
    const float* W     = (const float*)d_in[2];
    const float* gamma = (const float*)d_in[3];
    const float* beta  = (const float*)d_in[4];
    const float* rmean = (const float*)d_in[5];
    const float* rvar  = (const float*)d_in[6];
    float* out = (float*)d_out;

    char* ws = (char*)d_ws;
    short*          Wb    = (short*)(ws);
    float*          scale = (float*)(ws + 32768);
    float*          bias  = (float*)(ws + 33280);
    float4*         pts   = (float4*)(ws + 33792);
    unsigned short* knn   = (unsigned short*)(ws + 558080);
    short*          Zb    = (short*)(ws + 1606656);

    small_prep_kernel<<<BATCH * NPTS / 256, 256, 0, stream>>>(
        xyz, W, gamma, beta, rmean, rvar, Wb, scale, bias, pts);
    fused_kernel<<<512 + BATCH * NPTS / 16, 256, 0, stream>>>(x, pts, Wb, knn, Zb);
    gmax_kernel<<<BATCH * NPTS / 16, 256, 0, stream>>>(Zb, knn, scale, bias, out);
}